// Round 1
// baseline (398.243 us; speedup 1.0000x reference)
//
#include <hip/hip_runtime.h>

typedef unsigned short u16;
typedef float f32x4 __attribute__((ext_vector_type(4)));
typedef short s16x8 __attribute__((ext_vector_type(8)));
typedef unsigned short u16x4 __attribute__((ext_vector_type(4)));

#define EPS 1e-6f

static __device__ __forceinline__ u16 f2bf(float f) {
  unsigned u = __float_as_uint(f);
  u += 0x7fffu + ((u >> 16) & 1u);   // RNE
  return (u16)(u >> 16);
}
static __device__ __forceinline__ float bf2f(u16 h) {
  return __uint_as_float(((unsigned)h) << 16);
}

// ---------------- Stage 1: transpose weights to bf16 [col][k] ----------------
__global__ void wtrans_kernel(const float* __restrict__ Wq, const float* __restrict__ Wk,
                              const float* __restrict__ Wv,
                              u16* __restrict__ WqT, u16* __restrict__ WkT, u16* __restrict__ WvT) {
  int b = blockIdx.x;
  int mat = b >> 4, cg = b & 15;
  const float* W = mat == 0 ? Wq : (mat == 1 ? Wk : Wv);
  u16* WT = mat == 0 ? WqT : (mat == 1 ? WkT : WvT);
  int t = threadIdx.x;
  int c = cg * 16 + (t & 15);
  int k0 = (t >> 4) * 16;
  for (int i = 0; i < 16; ++i) {
    int k = k0 + i;
    WT[c * 256 + k] = f2bf(W[k * 256 + c]);
  }
}

// ---------------- Stage 2: Q,K,V GEMMs; write Qb [n][d], Kt/Vt [d][n] (bf16) ----------------
__global__ __launch_bounds__(256, 2)
void qkv_kernel(const float* __restrict__ x,
                const u16* __restrict__ WqT, const u16* __restrict__ WkT, const u16* __restrict__ WvT,
                const float* __restrict__ bq, const float* __restrict__ bk, const float* __restrict__ bv,
                u16* __restrict__ Qb, u16* __restrict__ Kt, u16* __restrict__ Vt,
                int N, int NPAD) {
  __shared__ u16 xs[128][264];   // x tile, bf16, +8 pad
  __shared__ u16 wst[128][40];   // W^T chunk [col][k 32 + 8 pad]
  const int tid = threadIdx.x;
  const int n0 = blockIdx.x * 128;

  // stage x tile (fp32 -> bf16), zero-pad rows >= N
  for (int i = 0; i < 32; ++i) {
    int l = tid + i * 256;
    int row = l >> 6;
    int c4 = (l & 63) << 2;
    int n = n0 + row;
    float4 v = make_float4(0.f, 0.f, 0.f, 0.f);
    if (n < N) v = *(const float4*)(x + (size_t)n * 256 + c4);
    xs[row][c4 + 0] = f2bf(v.x);
    xs[row][c4 + 1] = f2bf(v.y);
    xs[row][c4 + 2] = f2bf(v.z);
    xs[row][c4 + 3] = f2bf(v.w);
  }

  const int wave = tid >> 6, lane = tid & 63;
  const int quad = lane >> 4, l16 = lane & 15;
  const int wr = (wave >> 1) * 64;   // row (n) offset within tile
  const int wc = (wave & 1) * 64;    // col offset within 128-col half

  for (int ph = 0; ph < 6; ++ph) {   // {Q,K,V} x {colHalf 0,1}
    const int mat = ph >> 1;
    const int colBase = (ph & 1) * 128;
    const u16* WT = mat == 0 ? WqT : (mat == 1 ? WkT : WvT);
    const float* bias = mat == 0 ? bq : (mat == 1 ? bk : bv);
    f32x4 acc[4][4] = {};
    for (int kc = 0; kc < 256; kc += 32) {
      __syncthreads();
      for (int i = 0; i < 2; ++i) {
        int l = tid + i * 256;
        int col = l >> 2;
        int seg = (l & 3) << 3;
        *(s16x8*)&wst[col][seg] = *(const s16x8*)&WT[(size_t)(colBase + col) * 256 + kc + seg];
      }
      __syncthreads();
      s16x8 a[4], b[4];
      for (int f = 0; f < 4; ++f) a[f] = *(const s16x8*)&xs[wr + f * 16 + l16][kc + quad * 8];
      for (int f = 0; f < 4; ++f) b[f] = *(const s16x8*)&wst[wc + f * 16 + l16][quad * 8];
      for (int fr = 0; fr < 4; ++fr)
        for (int fc = 0; fc < 4; ++fc)
          acc[fr][fc] = __builtin_amdgcn_mfma_f32_16x16x32_bf16(a[fr], b[fc], acc[fr][fc], 0, 0, 0);
    }
    // epilogue: bias (+relu for Q,K), cast bf16, store
    for (int fc = 0; fc < 4; ++fc) {
      int colg = colBase + wc + fc * 16 + l16;
      float bb = bias[colg];
      for (int fr = 0; fr < 4; ++fr) {
        int nl = wr + fr * 16 + quad * 4;
        int n = n0 + nl;
        if (mat == 0) {
          for (int j = 0; j < 4; ++j) {
            float v = acc[fr][fc][j] + bb;
            v = fmaxf(v, 0.f);
            Qb[(size_t)(n + j) * 256 + colg] = (n + j < N) ? f2bf(v) : (u16)0;
          }
        } else {
          u16x4 pk;
          for (int j = 0; j < 4; ++j) {
            float v = acc[fr][fc][j] + bb;
            if (mat == 1) v = fmaxf(v, 0.f);
            pk[j] = (n + j < N) ? f2bf(v) : (u16)0;
          }
          u16* T = (mat == 1) ? Kt : Vt;
          *(u16x4*)&T[(size_t)colg * NPAD + n] = pk;
        }
      }
    }
  }
}

// ---------------- Stage 3: ksum[d] = sum_n K[n][d] (rows of Kt are contiguous) ----------------
__global__ void ksum_kernel(const u16* __restrict__ Kt, float* __restrict__ ksum, int NPAD) {
  int d = blockIdx.x;
  int t = threadIdx.x;
  const u16* row = Kt + (size_t)d * NPAD;
  float s = 0.f;
  int nu = NPAD >> 3;
  for (int j = t; j < nu; j += 256) {
    s16x8 v = *(const s16x8*)(row + j * 8);
    for (int e = 0; e < 8; ++e) s += bf2f((u16)v[e]);
  }
  for (int off = 32; off > 0; off >>= 1) s += __shfl_down(s, off);
  __shared__ float red[4];
  if ((t & 63) == 0) red[t >> 6] = s;
  __syncthreads();
  if (t == 0) ksum[d] = red[0] + red[1] + red[2] + red[3];
}

// ---------------- Stage 4a: KV^T partials: P[s][d][e] += sum_n V[n][e] K[n][d] ----------------
__global__ __launch_bounds__(256, 2)
void kv_kernel(const u16* __restrict__ Kt, const u16* __restrict__ Vt,
               float* __restrict__ P, int NPAD) {
  __shared__ u16 As[128][40];   // Vt rows (e)
  __shared__ u16 Bs[128][40];   // Kt rows (d)
  const int tid = threadIdx.x;
  const int s = blockIdx.x & 63;
  const int tile = blockIdx.x >> 6;
  const int ti = (tile >> 1) * 128;  // e base
  const int tj = (tile & 1) * 128;   // d base
  const int wave = tid >> 6, lane = tid & 63;
  const int quad = lane >> 4, l16 = lane & 15;
  const int we = (wave >> 1) * 64;
  const int wd = (wave & 1) * 64;
  f32x4 acc[4][4] = {};
  const int NCH = NPAD >> 5;
  for (int c = s; c < NCH; c += 64) {
    int nb = c << 5;
    __syncthreads();
    for (int i = 0; i < 2; ++i) {
      int l = tid + i * 256;
      int row = l >> 2;
      int seg = (l & 3) << 3;
      *(s16x8*)&As[row][seg] = *(const s16x8*)&Vt[(size_t)(ti + row) * NPAD + nb + seg];
      *(s16x8*)&Bs[row][seg] = *(const s16x8*)&Kt[(size_t)(tj + row) * NPAD + nb + seg];
    }
    __syncthreads();
    s16x8 a[4], b[4];
    for (int f = 0; f < 4; ++f) a[f] = *(const s16x8*)&As[we + f * 16 + l16][quad * 8];
    for (int f = 0; f < 4; ++f) b[f] = *(const s16x8*)&Bs[wd + f * 16 + l16][quad * 8];
    for (int fr = 0; fr < 4; ++fr)
      for (int fc = 0; fc < 4; ++fc)
        acc[fr][fc] = __builtin_amdgcn_mfma_f32_16x16x32_bf16(a[fr], b[fc], acc[fr][fc], 0, 0, 0);
  }
  float* Pp = P + (size_t)s * 65536;
  for (int fr = 0; fr < 4; ++fr)
    for (int fc = 0; fc < 4; ++fc) {
      int d = tj + wd + fc * 16 + l16;
      int e0 = ti + we + fr * 16 + quad * 4;
      *(f32x4*)&Pp[(size_t)d * 256 + e0] = acc[fr][fc];
    }
}

// ---------------- Stage 4b: reduce partials, emit KVtb[e][d] bf16 ----------------
__global__ void kvred_kernel(const float* __restrict__ P, u16* __restrict__ KVtb) {
  int d = blockIdx.x;
  int e = threadIdx.x;
  float s = 0.f;
  for (int sp = 0; sp < 64; ++sp) s += P[(size_t)sp * 65536 + d * 256 + e];
  KVtb[e * 256 + d] = f2bf(s);
}

// ---------------- Stage 5: out[r][e] = (Q @ KV)[r][e] / (Q[r].ksum + eps) ----------------
// computed as C[e][r] = sum_d KVtb[e][d] * Qb[r][d]  (both operands k-contiguous)
__global__ __launch_bounds__(256, 2)
void out_kernel(const u16* __restrict__ Qb, const u16* __restrict__ KVtb,
                const float* __restrict__ ksum, float* __restrict__ out,
                int N, int NPAD) {
  __shared__ u16 Qs[128][264];
  __shared__ u16 KVs[128][40];
  __shared__ float nrm[128];
  __shared__ float ks[256];
  const int tid = threadIdx.x;
  const int r0 = blockIdx.x * 128;

  for (int i = 0; i < 16; ++i) {
    int l = tid + i * 256;
    int row = l >> 5;
    int seg = (l & 31) << 3;
    *(s16x8*)&Qs[row][seg] = *(const s16x8*)&Qb[(size_t)(r0 + row) * 256 + seg];
  }
  ks[tid] = ksum[tid];
  __syncthreads();
  if (tid < 128) {
    float sacc = 0.f;
    for (int d = 0; d < 256; ++d) sacc += bf2f(Qs[tid][d]) * ks[d];
    nrm[tid] = sacc + EPS;
  }

  const int wave = tid >> 6, lane = tid & 63;
  const int quad = lane >> 4, l16 = lane & 15;
  const int we = (wave >> 1) * 64;    // e offset within 128-half
  const int wrw = (wave & 1) * 64;    // r offset
  for (int eh = 0; eh < 2; ++eh) {
    f32x4 acc[4][4] = {};
    for (int kc = 0; kc < 256; kc += 32) {
      __syncthreads();
      for (int i = 0; i < 2; ++i) {
        int l = tid + i * 256;
        int row = l >> 2;
        int seg = (l & 3) << 3;
        *(s16x8*)&KVs[row][seg] = *(const s16x8*)&KVtb[(size_t)(eh * 128 + row) * 256 + kc + seg];
      }
      __syncthreads();
      s16x8 a[4], b[4];
      for (int f = 0; f < 4; ++f) a[f] = *(const s16x8*)&KVs[we + f * 16 + l16][quad * 8];
      for (int f = 0; f < 4; ++f) b[f] = *(const s16x8*)&Qs[wrw + f * 16 + l16][kc + quad * 8];
      for (int fr = 0; fr < 4; ++fr)
        for (int fc = 0; fc < 4; ++fc)
          acc[fr][fc] = __builtin_amdgcn_mfma_f32_16x16x32_bf16(a[fr], b[fc], acc[fr][fc], 0, 0, 0);
    }
    for (int fc = 0; fc < 4; ++fc) {
      int rl = wrw + fc * 16 + l16;
      int rg = r0 + rl;
      float inv = 1.0f / nrm[rl];
      if (rg < N) {
        for (int fr = 0; fr < 4; ++fr) {
          int eg = eh * 128 + we + fr * 16 + quad * 4;
          f32x4 o;
          o[0] = acc[fr][fc][0] * inv;
          o[1] = acc[fr][fc][1] * inv;
          o[2] = acc[fr][fc][2] * inv;
          o[3] = acc[fr][fc][3] * inv;
          *(f32x4*)&out[(size_t)rg * 256 + eg] = o;
        }
      }
    }
  }
}

extern "C" void kernel_launch(void* const* d_in, const int* in_sizes, int n_in,
                              void* d_out, int out_size, void* d_ws, size_t ws_size,
                              hipStream_t stream) {
  const float* x  = (const float*)d_in[0];
  const float* Wq = (const float*)d_in[1];
  const float* bq = (const float*)d_in[2];
  const float* Wk = (const float*)d_in[3];
  const float* bk = (const float*)d_in[4];
  const float* Wv = (const float*)d_in[5];
  const float* bv = (const float*)d_in[6];
  float* out = (float*)d_out;

  int N = in_sizes[0] / 256;
  int NPAD = ((N + 127) / 128) * 128;
  int nblk = NPAD / 128;

  char* p = (char*)d_ws;
  size_t szT = (size_t)256 * NPAD * sizeof(u16);
  u16* Kt = (u16*)p; p += szT;
  u16* Vt = (u16*)p; p += szT;
  u16* Qb = (u16*)p; p += szT;
  float* P = (float*)p; p += (size_t)64 * 65536 * sizeof(float);
  u16* KVtb = (u16*)p; p += (size_t)65536 * sizeof(u16);
  float* ksum = (float*)p; p += 256 * sizeof(float);
  u16* WqT = (u16*)p; p += (size_t)65536 * sizeof(u16);
  u16* WkT = (u16*)p; p += (size_t)65536 * sizeof(u16);
  u16* WvT = (u16*)p; p += (size_t)65536 * sizeof(u16);

  wtrans_kernel<<<48, 256, 0, stream>>>(Wq, Wk, Wv, WqT, WkT, WvT);
  qkv_kernel<<<nblk, 256, 0, stream>>>(x, WqT, WkT, WvT, bq, bk, bv, Qb, Kt, Vt, N, NPAD);
  ksum_kernel<<<256, 256, 0, stream>>>(Kt, ksum, NPAD);
  kv_kernel<<<256, 256, 0, stream>>>(Kt, Vt, P, NPAD);
  kvred_kernel<<<256, 256, 0, stream>>>(P, KVtb);
  out_kernel<<<nblk, 256, 0, stream>>>(Qb, KVtb, ksum, out, N, NPAD);
}